// Round 1
// baseline (2731.936 us; speedup 1.0000x reference)
//
#include <hip/hip_runtime.h>

typedef _Float16 half8 __attribute__((ext_vector_type(8)));
typedef float floatx4 __attribute__((ext_vector_type(4)));

#define T_LEN 2048
#define HST 264   // padded LDS row stride in f16 elems (264*2B = 528B, 16B-aligned, good bank spread)

// ---------------- Kernel 1: per-token tables + Wh cast ----------------
// WxE[v][e] = sum_d E[v][d]*Wx[e][d]; gE[v][e] = sigmoid(sum_d E[v][d]*Wz[e][d]);
// Whf[e][d] = (f16)Wh[e][d]  (row-major: B-frag for mfma is 8 contiguous d's)
__global__ __launch_bounds__(256) void precompute_k(
    const float* __restrict__ E, const float* __restrict__ Wx,
    const float* __restrict__ Wh, const float* __restrict__ Wz,
    float* __restrict__ WxE, float* __restrict__ gE, _Float16* __restrict__ Whf)
{
    const int v = blockIdx.x, e = threadIdx.x;
    __shared__ float Ev[256];
    Ev[e] = E[v * 256 + e];
    __syncthreads();
    float ax = 0.f, az = 0.f;
    #pragma unroll 4
    for (int d = 0; d < 256; d += 4) {
        float4 ev = *(const float4*)&Ev[d];
        float4 wx = *(const float4*)&Wx[e * 256 + d];
        float4 wz = *(const float4*)&Wz[e * 256 + d];
        ax += ev.x * wx.x + ev.y * wx.y + ev.z * wx.z + ev.w * wx.w;
        az += ev.x * wz.x + ev.y * wz.y + ev.z * wz.z + ev.w * wz.w;
    }
    WxE[v * 256 + e] = ax;
    gE[v * 256 + e]  = 1.f / (1.f + __expf(-az));
    Whf[v * 256 + e] = (_Float16)Wh[v * 256 + e];
}

// ---------------- Kernel 2: the serial recurrence ----------------
// 4 WGs x 16 batches. 8 waves/WG; wave wv owns output dims [wv*32, wv*32+32).
// Wh chunk lives in registers as B-frags for the whole kernel.
// h double-buffered in LDS (f16). One __syncthreads per timestep.
// y = h * gate stored fp32 into d_out (same bytes the logits will later occupy).
__global__ __launch_bounds__(512, 2) void rnn_k(
    const int* __restrict__ tokens, const float* __restrict__ WxE,
    const float* __restrict__ gE, const _Float16* __restrict__ Whf,
    float* __restrict__ y)
{
    const int tid = threadIdx.x;
    const int wv  = tid >> 6;        // 0..7
    const int l   = tid & 63;
    const int n   = l & 15;          // MFMA col (dim within 16-tile)
    const int q   = l >> 4;          // 0..3
    const int bbase = blockIdx.x << 4;
    const int r0  = q << 2;          // C-layout rows this lane owns
    const int e0  = (wv << 5) + n;   // tile0 dim; tile1 = e0 + 16

    // B fragments: Wh[e][d0..d0+7], d0 = q*8 + ks*32  (B[k][n] layout: n=l&15, k=q*8+j)
    half8 bf[2][8];
    #pragma unroll
    for (int tn = 0; tn < 2; ++tn) {
        const int e = e0 + (tn << 4);
        #pragma unroll
        for (int ks = 0; ks < 8; ++ks)
            bf[tn][ks] = *(const half8*)(Whf + e * 256 + (q << 3) + (ks << 5));
    }

    __shared__ _Float16 hbuf[2][16 * HST];
    for (int i = tid; i < 16 * HST; i += 512) hbuf[0][i] = (_Float16)0.f;
    __syncthreads();

    // 2-deep software pipeline: tokens fetched for t+2, wx/g gathered for t+1
    int tokn[4];
    float wxc[4][2], gc[4][2], wxn[4][2], gn[4][2];
    {
        int tok0[4];
        #pragma unroll
        for (int i = 0; i < 4; ++i) tok0[i] = tokens[(bbase + r0 + i) * T_LEN + 0];
        #pragma unroll
        for (int i = 0; i < 4; ++i) tokn[i] = tokens[(bbase + r0 + i) * T_LEN + 1];
        #pragma unroll
        for (int i = 0; i < 4; ++i) {
            const float* wp = WxE + tok0[i] * 256 + e0;
            const float* gp = gE  + tok0[i] * 256 + e0;
            wxc[i][0] = wp[0]; wxc[i][1] = wp[16];
            gc[i][0]  = gp[0]; gc[i][1]  = gp[16];
        }
    }

    #pragma unroll 2
    for (int t = 0; t < T_LEN; ++t) {
        const int rb = t & 1;
        // prefetch tokens for t+2
        const int t2 = (t + 2 < T_LEN) ? (t + 2) : (T_LEN - 1);
        int tok2[4];
        #pragma unroll
        for (int i = 0; i < 4; ++i) tok2[i] = tokens[(bbase + r0 + i) * T_LEN + t2];
        // gather wx/gate for t+1 (tokens resident since last iter)
        #pragma unroll
        for (int i = 0; i < 4; ++i) {
            const float* wp = WxE + tokn[i] * 256 + e0;
            const float* gp = gE  + tokn[i] * 256 + e0;
            wxn[i][0] = wp[0]; wxn[i][1] = wp[16];
            gn[i][0]  = gp[0]; gn[i][1]  = gp[16];
        }
        // matvec: A = h_{t-1}[16 x 256] from LDS, B = Wh chunk (registers)
        floatx4 acc0 = 0.f, acc1 = 0.f;
        const _Float16* hrow = &hbuf[rb][n * HST + (q << 3)];
        #pragma unroll
        for (int ks = 0; ks < 8; ++ks) {
            half8 a = *(const half8*)(hrow + (ks << 5));
            acc0 = __builtin_amdgcn_mfma_f32_16x16x32_f16(a, bf[0][ks], acc0, 0, 0, 0);
            acc1 = __builtin_amdgcn_mfma_f32_16x16x32_f16(a, bf[1][ks], acc1, 0, 0, 0);
        }
        // epilogue: preact(+wx in fp32) -> tanh -> y store + h_new to other LDS buffer
        _Float16* hw = &hbuf[rb ^ 1][0];
        #pragma unroll
        for (int r = 0; r < 4; ++r) {
            const int row = r0 + r;
            float p0 = acc0[r] + wxc[r][0];
            float p1 = acc1[r] + wxc[r][1];
            float ex0 = __expf(2.f * p0), ex1 = __expf(2.f * p1);
            float h0 = 1.f - 2.f / (ex0 + 1.f);   // tanh, branchless (inf-safe)
            float h1 = 1.f - 2.f / (ex1 + 1.f);
            float* yp = y + ((bbase + row) * T_LEN + t) * 256 + e0;
            yp[0]  = h0 * gc[r][0];
            yp[16] = h1 * gc[r][1];
            hw[row * HST + e0]      = (_Float16)h0;
            hw[row * HST + e0 + 16] = (_Float16)h1;
        }
        // rotate pipeline regs
        #pragma unroll
        for (int i = 0; i < 4; ++i) {
            wxc[i][0] = wxn[i][0]; wxc[i][1] = wxn[i][1];
            gc[i][0]  = gn[i][0];  gc[i][1]  = gn[i][1];
            tokn[i]   = tok2[i];
        }
        __syncthreads();
    }
}

// ---------------- Kernel 3: tied head, in place ----------------
// logits[r][v] = sum_d y[r][d] * E[v][d]. Each WG owns 64 rows of d_out:
// read its y rows into MFMA A-frags (fp32->fp16), barrier, overwrite with logits.
__device__ inline half8 cvt8(const float* p) {
    float4 u = *(const float4*)p;
    float4 w = *(const float4*)(p + 4);
    half8 r;
    r[0] = (_Float16)u.x; r[1] = (_Float16)u.y; r[2] = (_Float16)u.z; r[3] = (_Float16)u.w;
    r[4] = (_Float16)w.x; r[5] = (_Float16)w.y; r[6] = (_Float16)w.z; r[7] = (_Float16)w.w;
    return r;
}

__global__ __launch_bounds__(256) void logits_k(
    const float* __restrict__ E, float* __restrict__ io)
{
    const int tid = threadIdx.x;
    const int wv = tid >> 6;             // v-chunk base = wv*64
    const int l  = tid & 63;
    const int n  = l & 15, q = l >> 4;
    const int rowbase = blockIdx.x << 6; // 64 rows per WG
    const int k0base = q << 3;

    floatx4 acc[4][4];
    #pragma unroll
    for (int mt = 0; mt < 4; ++mt)
        #pragma unroll
        for (int tn = 0; tn < 4; ++tn) acc[mt][tn] = 0.f;

    #pragma unroll
    for (int ks = 0; ks < 8; ++ks) {
        const int k0 = (ks << 5) + k0base;
        half8 a[4], b[4];
        #pragma unroll
        for (int mt = 0; mt < 4; ++mt)
            a[mt] = cvt8(io + (rowbase + (mt << 4) + n) * 256 + k0);
        #pragma unroll
        for (int tn = 0; tn < 4; ++tn)
            b[tn] = cvt8(E + ((wv << 6) + (tn << 4) + n) * 256 + k0);
        #pragma unroll
        for (int mt = 0; mt < 4; ++mt)
            #pragma unroll
            for (int tn = 0; tn < 4; ++tn)
                acc[mt][tn] = __builtin_amdgcn_mfma_f32_16x16x32_f16(a[mt], b[tn], acc[mt][tn], 0, 0, 0);
    }
    __syncthreads();  // every wave's y reads complete before anyone overwrites
    #pragma unroll
    for (int mt = 0; mt < 4; ++mt)
        #pragma unroll
        for (int tn = 0; tn < 4; ++tn)
            #pragma unroll
            for (int r = 0; r < 4; ++r)
                io[(rowbase + (mt << 4) + (q << 2) + r) * 256 + (wv << 6) + (tn << 4) + n] = acc[mt][tn][r];
}

// ---------------- host ----------------
extern "C" void kernel_launch(void* const* d_in, const int* in_sizes, int n_in,
                              void* d_out, int out_size, void* d_ws, size_t ws_size,
                              hipStream_t stream) {
    const int*   tokens = (const int*)d_in[0];
    const float* E      = (const float*)d_in[1];
    const float* Wx     = (const float*)d_in[2];
    const float* Wh     = (const float*)d_in[3];
    const float* Wz     = (const float*)d_in[4];
    float* out = (float*)d_out;

    char* ws = (char*)d_ws;
    float*    WxE = (float*)ws;                       // 256 KiB
    float*    gEt = (float*)(ws + (256 << 10));       // 256 KiB
    _Float16* Whf = (_Float16*)(ws + (512 << 10));    // 128 KiB

    precompute_k<<<256, 256, 0, stream>>>(E, Wx, Wh, Wz, WxE, gEt, Whf);
    rnn_k<<<4, 512, 0, stream>>>(tokens, WxE, gEt, Whf, out);
    logits_k<<<2048, 256, 0, stream>>>(E, out);
}

// Round 2
// 2382.959 us; speedup vs baseline: 1.1464x; 1.1464x over previous
//
#include <hip/hip_runtime.h>

typedef _Float16 half8 __attribute__((ext_vector_type(8)));
typedef float floatx4 __attribute__((ext_vector_type(4)));

#define T_LEN 2048
#define HST 264   // padded LDS row stride in f16 elems (528B rows, 16B-aligned)

// LDS-only barrier: waits ds ops, does NOT drain vmcnt (global loads/stores stay in flight)
#define LDS_BARRIER() asm volatile("s_waitcnt lgkmcnt(0)\n\ts_barrier" ::: "memory")

// ---------------- Kernel 1: fused per-token table + Wh cast ----------------
// wgt[v*256+e] = { sum_d E[v][d]*Wx[e][d], sigmoid(sum_d E[v][d]*Wz[e][d]) }
// Whf[e][d] = (f16)Wh[e][d]
__global__ __launch_bounds__(256) void precompute_k(
    const float* __restrict__ E, const float* __restrict__ Wx,
    const float* __restrict__ Wh, const float* __restrict__ Wz,
    float2* __restrict__ wgt, _Float16* __restrict__ Whf)
{
    const int v = blockIdx.x, e = threadIdx.x;
    __shared__ float Ev[256];
    Ev[e] = E[v * 256 + e];
    __syncthreads();
    float ax = 0.f, az = 0.f;
    #pragma unroll 4
    for (int d = 0; d < 256; d += 4) {
        float4 ev = *(const float4*)&Ev[d];
        float4 wx = *(const float4*)&Wx[e * 256 + d];
        float4 wz = *(const float4*)&Wz[e * 256 + d];
        ax += ev.x * wx.x + ev.y * wx.y + ev.z * wx.z + ev.w * wx.w;
        az += ev.x * wz.x + ev.y * wz.y + ev.z * wz.z + ev.w * wz.w;
    }
    float2 o; o.x = ax; o.y = 1.f / (1.f + __expf(-az));
    wgt[v * 256 + e] = o;
    Whf[v * 256 + e] = (_Float16)Wh[v * 256 + e];
}

// ---------------- Kernel 2: the serial recurrence ----------------
// 4 WGs x 16 batches, 8 waves/WG; wave wv owns dims [wv*32, wv*32+32).
// Wh chunk in registers (B-frags) for the whole kernel; h double-buffered in LDS.
// One LDS-only barrier per timestep; global traffic never drained in-loop.
__global__ __launch_bounds__(512, 2) void rnn_k(
    const int* __restrict__ tokens, const float2* __restrict__ wgt,
    const _Float16* __restrict__ Whf, float* __restrict__ y)
{
    const int tid = threadIdx.x;
    const int wv  = tid >> 6;        // 0..7
    const int l   = tid & 63;
    const int n   = l & 15;          // MFMA col (dim within 16-tile)
    const int q   = l >> 4;          // 0..3
    const int bbase = blockIdx.x << 4;
    const int r0  = q << 2;          // C-layout rows this lane owns
    const int e0  = (wv << 5) + n;   // tile0 dim; tile1 = e0 + 16

    // B fragments: Wh[e][d0..d0+7], d0 = q*8 + ks*32  (B[k][n]: n=l&15, k=q*8+j)
    half8 bf[2][8];
    #pragma unroll
    for (int tn = 0; tn < 2; ++tn) {
        const int e = e0 + (tn << 4);
        #pragma unroll
        for (int ks = 0; ks < 8; ++ks)
            bf[tn][ks] = *(const half8*)(Whf + e * 256 + (q << 3) + (ks << 5));
    }

    __shared__ _Float16 hbuf[2][16 * HST];
    for (int i = tid; i < 16 * HST; i += 512) hbuf[0][i] = (_Float16)0.f;
    LDS_BARRIER();

    // per-lane persistent pointers (incremented, no per-step mul chains)
    const int* tp[4];
    float* yrow[4];
    #pragma unroll
    for (int i = 0; i < 4; ++i) {
        const int row = bbase + r0 + i;
        tp[i]   = tokens + (size_t)row * T_LEN;
        yrow[i] = y + (size_t)row * T_LEN * 256 + e0;
    }
    const int hoff = r0 * HST + e0;
    const _Float16* hrd = &hbuf[0][n * HST + (q << 3)];

    // 2-deep pipeline: tokens at t+2, wx/g gathered at t+1
    int tokn[4];
    float wxc[4][2], gc[4][2], wxn[4][2], gn[4][2];
    {
        #pragma unroll
        for (int i = 0; i < 4; ++i) {
            const int t0 = tp[i][0];
            tokn[i] = tp[i][1];
            const float2* gp = wgt + ((size_t)t0 << 8) + e0;
            float2 a = gp[0], b = gp[16];
            wxc[i][0] = a.x; gc[i][0] = a.y;
            wxc[i][1] = b.x; gc[i][1] = b.y;
        }
    }

    #pragma unroll 2
    for (int t = 0; t < T_LEN; ++t) {
        const int rb = t & 1;
        // prefetch tokens for t+2 (uniform clamp)
        const int t2 = (t + 2 < T_LEN) ? (t + 2) : (T_LEN - 1);
        int tok2[4];
        #pragma unroll
        for (int i = 0; i < 4; ++i) tok2[i] = tp[i][t2];
        // gather wx/gate for t+1 (consumed next iter; never drained by barrier)
        #pragma unroll
        for (int i = 0; i < 4; ++i) {
            const float2* gp = wgt + ((size_t)tokn[i] << 8) + e0;
            float2 a = gp[0], b = gp[16];
            wxn[i][0] = a.x; gn[i][0] = a.y;
            wxn[i][1] = b.x; gn[i][1] = b.y;
        }
        // matvec: A = h_{t-1}[16 x 256] from LDS, B = Wh chunk (registers)
        floatx4 acc0 = 0.f, acc1 = 0.f;
        const _Float16* hrow = hrd + rb * (16 * HST);
        #pragma unroll
        for (int ks = 0; ks < 8; ++ks) {
            half8 a = *(const half8*)(hrow + (ks << 5));
            acc0 = __builtin_amdgcn_mfma_f32_16x16x32_f16(a, bf[0][ks], acc0, 0, 0, 0);
            acc1 = __builtin_amdgcn_mfma_f32_16x16x32_f16(a, bf[1][ks], acc1, 0, 0, 0);
        }
        // epilogue: preact -> tanh (exp2 + rcp, no exact-div) -> y store + h to LDS
        _Float16* hw = &hbuf[rb ^ 1][hoff];
        #pragma unroll
        for (int r = 0; r < 4; ++r) {
            float p0 = acc0[r] + wxc[r][0];
            float p1 = acc1[r] + wxc[r][1];
            float ex0 = __builtin_amdgcn_exp2f(p0 * 2.885390082f);  // e^{2p}
            float ex1 = __builtin_amdgcn_exp2f(p1 * 2.885390082f);
            float h0 = fmaf(__builtin_amdgcn_rcpf(ex0 + 1.f), -2.f, 1.f);  // tanh, inf-safe
            float h1 = fmaf(__builtin_amdgcn_rcpf(ex1 + 1.f), -2.f, 1.f);
            yrow[r][0]  = h0 * gc[r][0];
            yrow[r][16] = h1 * gc[r][1];
            hw[r * HST]      = (_Float16)h0;
            hw[r * HST + 16] = (_Float16)h1;
        }
        // rotate pipeline regs, advance store pointers
        #pragma unroll
        for (int i = 0; i < 4; ++i) {
            wxc[i][0] = wxn[i][0]; wxc[i][1] = wxn[i][1];
            gc[i][0]  = gn[i][0];  gc[i][1]  = gn[i][1];
            tokn[i]   = tok2[i];
            yrow[i]  += 256;
        }
        LDS_BARRIER();   // LDS visibility only; y-stores/gathers stay in flight
    }
}

// ---------------- Kernel 3: tied head, in place ----------------
__device__ inline half8 cvt8(const float* p) {
    float4 u = *(const float4*)p;
    float4 w = *(const float4*)(p + 4);
    half8 r;
    r[0] = (_Float16)u.x; r[1] = (_Float16)u.y; r[2] = (_Float16)u.z; r[3] = (_Float16)u.w;
    r[4] = (_Float16)w.x; r[5] = (_Float16)w.y; r[6] = (_Float16)w.z; r[7] = (_Float16)w.w;
    return r;
}

__global__ __launch_bounds__(256) void logits_k(
    const float* __restrict__ E, float* __restrict__ io)
{
    const int tid = threadIdx.x;
    const int wv = tid >> 6;             // v-chunk base = wv*64
    const int l  = tid & 63;
    const int n  = l & 15, q = l >> 4;
    const int rowbase = blockIdx.x << 6; // 64 rows per WG
    const int k0base = q << 3;

    floatx4 acc[4][4];
    #pragma unroll
    for (int mt = 0; mt < 4; ++mt)
        #pragma unroll
        for (int tn = 0; tn < 4; ++tn) acc[mt][tn] = 0.f;

    #pragma unroll
    for (int ks = 0; ks < 8; ++ks) {
        const int k0 = (ks << 5) + k0base;
        half8 a[4], b[4];
        #pragma unroll
        for (int mt = 0; mt < 4; ++mt)
            a[mt] = cvt8(io + (rowbase + (mt << 4) + n) * 256 + k0);
        #pragma unroll
        for (int tn = 0; tn < 4; ++tn)
            b[tn] = cvt8(E + ((wv << 6) + (tn << 4) + n) * 256 + k0);
        #pragma unroll
        for (int mt = 0; mt < 4; ++mt)
            #pragma unroll
            for (int tn = 0; tn < 4; ++tn)
                acc[mt][tn] = __builtin_amdgcn_mfma_f32_16x16x32_f16(a[mt], b[tn], acc[mt][tn], 0, 0, 0);
    }
    __syncthreads();  // every wave's y reads complete before anyone overwrites
    #pragma unroll
    for (int mt = 0; mt < 4; ++mt)
        #pragma unroll
        for (int tn = 0; tn < 4; ++tn)
            #pragma unroll
            for (int r = 0; r < 4; ++r)
                io[(rowbase + (mt << 4) + (q << 2) + r) * 256 + (wv << 6) + (tn << 4) + n] = acc[mt][tn][r];
}

// ---------------- host ----------------
extern "C" void kernel_launch(void* const* d_in, const int* in_sizes, int n_in,
                              void* d_out, int out_size, void* d_ws, size_t ws_size,
                              hipStream_t stream) {
    const int*   tokens = (const int*)d_in[0];
    const float* E      = (const float*)d_in[1];
    const float* Wx     = (const float*)d_in[2];
    const float* Wh     = (const float*)d_in[3];
    const float* Wz     = (const float*)d_in[4];
    float* out = (float*)d_out;

    char* ws = (char*)d_ws;
    float2*   wgt = (float2*)ws;                      // 512 KiB
    _Float16* Whf = (_Float16*)(ws + (512 << 10));    // 128 KiB

    precompute_k<<<256, 256, 0, stream>>>(E, Wx, Wh, Wz, wgt, Whf);
    rnn_k<<<4, 512, 0, stream>>>(tokens, wgt, Whf, out);
    logits_k<<<2048, 256, 0, stream>>>(E, out);
}

// Round 3
// 2373.760 us; speedup vs baseline: 1.1509x; 1.0039x over previous
//
#include <hip/hip_runtime.h>

typedef _Float16 half8 __attribute__((ext_vector_type(8)));
typedef float floatx4 __attribute__((ext_vector_type(4)));

#define T_LEN 2048
#define HST 264   // padded LDS row stride in f16 elems (528B rows, 16B-aligned)

// LDS-only barrier: waits ds ops, does NOT drain vmcnt (globals stay in flight)
#define LDS_BARRIER() asm volatile("s_waitcnt lgkmcnt(0)\n\ts_barrier" ::: "memory")

// ---------------- Kernel 1: fused per-token table + Wh cast ----------------
__global__ __launch_bounds__(256) void precompute_k(
    const float* __restrict__ E, const float* __restrict__ Wx,
    const float* __restrict__ Wh, const float* __restrict__ Wz,
    float2* __restrict__ wgt, _Float16* __restrict__ Whf)
{
    const int v = blockIdx.x, e = threadIdx.x;
    __shared__ float Ev[256];
    Ev[e] = E[v * 256 + e];
    __syncthreads();
    float ax = 0.f, az = 0.f;
    #pragma unroll 4
    for (int d = 0; d < 256; d += 4) {
        float4 ev = *(const float4*)&Ev[d];
        float4 wx = *(const float4*)&Wx[e * 256 + d];
        float4 wz = *(const float4*)&Wz[e * 256 + d];
        ax += ev.x * wx.x + ev.y * wx.y + ev.z * wx.z + ev.w * wx.w;
        az += ev.x * wz.x + ev.y * wz.y + ev.z * wz.z + ev.w * wz.w;
    }
    float2 o; o.x = ax; o.y = 1.f / (1.f + __expf(-az));
    wgt[v * 256 + e] = o;
    Whf[v * 256 + e] = (_Float16)Wh[v * 256 + e];
}

// ---------------- Kernel 2: the serial recurrence ----------------
// 4 WGs x 16 batches, 8 waves/WG; wave wv owns dims [wv*32, wv*32+32).
// Wh chunk in registers/AGPRs (B-frags). h double-buffered in LDS.
// Tokens staged in LDS transposed (u8). Gathers issued 2 steps ahead.
__global__ __launch_bounds__(512, 2) void rnn_k(
    const int* __restrict__ tokens, const float2* __restrict__ wgt,
    const _Float16* __restrict__ Whf, float* __restrict__ y)
{
    const int tid = threadIdx.x;
    const int wv  = tid >> 6;        // 0..7
    const int l   = tid & 63;
    const int n   = l & 15;          // MFMA col within 16-tile
    const int q   = l >> 4;          // 0..3
    const int bbase = blockIdx.x << 4;
    const int r0  = q << 2;          // C-layout rows this lane owns
    const int e0  = (wv << 5) + n;   // tile0 dim; tile1 = e0 + 16

    // B fragments: Wh[e][d0..d0+7], d0 = q*8 + ks*32
    half8 bf[2][8];
    #pragma unroll
    for (int tn = 0; tn < 2; ++tn) {
        const int e = e0 + (tn << 4);
        #pragma unroll
        for (int ks = 0; ks < 8; ++ks)
            bf[tn][ks] = *(const half8*)(Whf + e * 256 + (q << 3) + (ks << 5));
    }

    __shared__ _Float16 hbuf[2][16 * HST];          // 16.9 KB
    __shared__ unsigned char tokT[T_LEN * 16];      // 32 KB, tokT[t*16+row]

    // stage this WG's tokens transposed (one-time; coalesced along t)
    for (int i = tid; i < 16 * T_LEN; i += 512) {
        const int row = i >> 11, t = i & (T_LEN - 1);
        tokT[t * 16 + row] = (unsigned char)tokens[(bbase + row) * T_LEN + t];
    }
    for (int i = tid; i < 16 * HST; i += 512) hbuf[0][i] = (_Float16)0.f;
    LDS_BARRIER();

    // y element-index bases (32-bit, saddr-friendly stores)
    unsigned int yidx[4];
    #pragma unroll
    for (int i = 0; i < 4; ++i)
        yidx[i] = (unsigned)((bbase + r0 + i) * (T_LEN * 256) + e0);

    const _Float16* hrd0 = &hbuf[0][n * HST + (q << 3)];
    const _Float16* hrd1 = &hbuf[1][n * HST + (q << 3)];
    _Float16* hw0 = &hbuf[0][r0 * HST + e0];
    _Float16* hw1 = &hbuf[1][r0 * HST + e0];

    // prologue: fetch wx/gate for t=0 (even set) and t=1 (odd set)
    float wxe[4][2], ge[4][2], wxo[4][2], go[4][2];
    {
        const unsigned int t0 = *(const unsigned int*)&tokT[0 * 16 + r0];
        const unsigned int t1 = *(const unsigned int*)&tokT[1 * 16 + r0];
        #pragma unroll
        for (int i = 0; i < 4; ++i) {
            const int ta = (t0 >> (8 * i)) & 255;
            const int tb = (t1 >> (8 * i)) & 255;
            const float2* gp = wgt + ta * 256 + e0;
            float2 a = gp[0], b = gp[16];
            wxe[i][0] = a.x; ge[i][0] = a.y; wxe[i][1] = b.x; ge[i][1] = b.y;
            const float2* hp = wgt + tb * 256 + e0;
            float2 c = hp[0], d = hp[16];
            wxo[i][0] = c.x; go[i][0] = c.y; wxo[i][1] = d.x; go[i][1] = d.y;
        }
    }

// One timestep. Reads HRD (h_{t-1}), writes HW (h_t). Consumes WX/G (fetched
// 2 steps ago), refills them for tcur+2 via LDS tokens + L2 gather.
#define STEP(tcur, HRD, HW, WX, G)                                             \
    {                                                                          \
        int tf = (tcur) + 2; if (tf > T_LEN - 1) tf = T_LEN - 1;               \
        const unsigned int tok4 = *(const unsigned int*)&tokT[tf * 16 + r0];   \
        floatx4 acc0a = 0.f, acc0b = 0.f, acc1a = 0.f, acc1b = 0.f;            \
        _Pragma("unroll")                                                      \
        for (int ks = 0; ks < 8; ks += 2) {                                    \
            half8 a0 = *(const half8*)(HRD + (ks << 5));                       \
            half8 a1 = *(const half8*)(HRD + ((ks + 1) << 5));                 \
            acc0a = __builtin_amdgcn_mfma_f32_16x16x32_f16(a0, bf[0][ks],     acc0a, 0, 0, 0); \
            acc1a = __builtin_amdgcn_mfma_f32_16x16x32_f16(a0, bf[1][ks],     acc1a, 0, 0, 0); \
            acc0b = __builtin_amdgcn_mfma_f32_16x16x32_f16(a1, bf[0][ks + 1], acc0b, 0, 0, 0); \
            acc1b = __builtin_amdgcn_mfma_f32_16x16x32_f16(a1, bf[1][ks + 1], acc1b, 0, 0, 0); \
        }                                                                      \
        float nwx[4][2], ng[4][2];                                             \
        _Pragma("unroll")                                                      \
        for (int i = 0; i < 4; ++i) {                                          \
            const int tk = (tok4 >> (8 * i)) & 255;                            \
            const float2* gp = wgt + tk * 256 + e0;                            \
            float2 a = gp[0], b = gp[16];                                      \
            nwx[i][0] = a.x; ng[i][0] = a.y; nwx[i][1] = b.x; ng[i][1] = b.y;  \
        }                                                                      \
        _Pragma("unroll")                                                      \
        for (int r = 0; r < 4; ++r) {                                          \
            float p0 = (acc0a[r] + acc0b[r]) + WX[r][0];                       \
            float p1 = (acc1a[r] + acc1b[r]) + WX[r][1];                       \
            float ex0 = __builtin_amdgcn_exp2f(p0 * 2.885390082f);             \
            float ex1 = __builtin_amdgcn_exp2f(p1 * 2.885390082f);             \
            float h0 = fmaf(__builtin_amdgcn_rcpf(ex0 + 1.f), -2.f, 1.f);      \
            float h1 = fmaf(__builtin_amdgcn_rcpf(ex1 + 1.f), -2.f, 1.f);      \
            __builtin_nontemporal_store(h0 * G[r][0], &y[yidx[r]]);            \
            __builtin_nontemporal_store(h1 * G[r][1], &y[yidx[r] + 16]);       \
            HW[r * HST]      = (_Float16)h0;                                   \
            HW[r * HST + 16] = (_Float16)h1;                                   \
            yidx[r] += 256;                                                    \
        }                                                                      \
        _Pragma("unroll")                                                      \
        for (int i = 0; i < 4; ++i) {                                          \
            WX[i][0] = nwx[i][0]; WX[i][1] = nwx[i][1];                        \
            G[i][0]  = ng[i][0];  G[i][1]  = ng[i][1];                         \
        }                                                                      \
        LDS_BARRIER();                                                         \
    }

    for (int t = 0; t < T_LEN; t += 2) {
        STEP(t,     hrd0, hw1, wxe, ge)   // even: h_{t-1} in buf0, h_t -> buf1
        STEP(t + 1, hrd1, hw0, wxo, go)   // odd:  h_t in buf1, h_{t+1} -> buf0
    }
#undef STEP
}

// ---------------- Kernel 3: tied head, in place ----------------
__device__ inline half8 cvt8(const float* p) {
    float4 u = *(const float4*)p;
    float4 w = *(const float4*)(p + 4);
    half8 r;
    r[0] = (_Float16)u.x; r[1] = (_Float16)u.y; r[2] = (_Float16)u.z; r[3] = (_Float16)u.w;
    r[4] = (_Float16)w.x; r[5] = (_Float16)w.y; r[6] = (_Float16)w.z; r[7] = (_Float16)w.w;
    return r;
}

__global__ __launch_bounds__(256) void logits_k(
    const float* __restrict__ E, float* __restrict__ io)
{
    const int tid = threadIdx.x;
    const int wv = tid >> 6;             // v-chunk base = wv*64
    const int l  = tid & 63;
    const int n  = l & 15, q = l >> 4;
    const int rowbase = blockIdx.x << 6; // 64 rows per WG
    const int k0base = q << 3;

    floatx4 acc[4][4];
    #pragma unroll
    for (int mt = 0; mt < 4; ++mt)
        #pragma unroll
        for (int tn = 0; tn < 4; ++tn) acc[mt][tn] = 0.f;

    #pragma unroll
    for (int ks = 0; ks < 8; ++ks) {
        const int k0 = (ks << 5) + k0base;
        half8 a[4], b[4];
        #pragma unroll
        for (int mt = 0; mt < 4; ++mt)
            a[mt] = cvt8(io + (rowbase + (mt << 4) + n) * 256 + k0);
        #pragma unroll
        for (int tn = 0; tn < 4; ++tn)
            b[tn] = cvt8(E + ((wv << 6) + (tn << 4) + n) * 256 + k0);
        #pragma unroll
        for (int mt = 0; mt < 4; ++mt)
            #pragma unroll
            for (int tn = 0; tn < 4; ++tn)
                acc[mt][tn] = __builtin_amdgcn_mfma_f32_16x16x32_f16(a[mt], b[tn], acc[mt][tn], 0, 0, 0);
    }
    __syncthreads();  // every wave's y reads complete before anyone overwrites
    #pragma unroll
    for (int mt = 0; mt < 4; ++mt)
        #pragma unroll
        for (int tn = 0; tn < 4; ++tn)
            #pragma unroll
            for (int r = 0; r < 4; ++r)
                io[(rowbase + (mt << 4) + (q << 2) + r) * 256 + (wv << 6) + (tn << 4) + n] = acc[mt][tn][r];
}

// ---------------- host ----------------
extern "C" void kernel_launch(void* const* d_in, const int* in_sizes, int n_in,
                              void* d_out, int out_size, void* d_ws, size_t ws_size,
                              hipStream_t stream) {
    const int*   tokens = (const int*)d_in[0];
    const float* E      = (const float*)d_in[1];
    const float* Wx     = (const float*)d_in[2];
    const float* Wh     = (const float*)d_in[3];
    const float* Wz     = (const float*)d_in[4];
    float* out = (float*)d_out;

    char* ws = (char*)d_ws;
    float2*   wgt = (float2*)ws;                      // 512 KiB
    _Float16* Whf = (_Float16*)(ws + (512 << 10));    // 128 KiB

    precompute_k<<<256, 256, 0, stream>>>(E, Wx, Wh, Wz, wgt, Whf);
    rnn_k<<<4, 512, 0, stream>>>(tokens, wgt, Whf, out);
    logits_k<<<2048, 256, 0, stream>>>(E, out);
}

// Round 4
// 2331.547 us; speedup vs baseline: 1.1717x; 1.0181x over previous
//
#include <hip/hip_runtime.h>

typedef _Float16 half8 __attribute__((ext_vector_type(8)));
typedef float floatx4 __attribute__((ext_vector_type(4)));

#define T_LEN 2048
#define HST 264   // padded LDS row stride in f16 elems (528B rows, 16B-aligned)

// LDS-only barrier: waits ds ops, does NOT drain vmcnt (globals stay in flight)
#define LDS_BARRIER() asm volatile("s_waitcnt lgkmcnt(0)\n\ts_barrier" ::: "memory")

// ---------------- Kernel 1: fused per-token table + Wh cast ----------------
__global__ __launch_bounds__(256) void precompute_k(
    const float* __restrict__ E, const float* __restrict__ Wx,
    const float* __restrict__ Wh, const float* __restrict__ Wz,
    float2* __restrict__ wgt, _Float16* __restrict__ Whf)
{
    const int v = blockIdx.x, e = threadIdx.x;
    __shared__ float Ev[256];
    Ev[e] = E[v * 256 + e];
    __syncthreads();
    float ax = 0.f, az = 0.f;
    #pragma unroll 4
    for (int d = 0; d < 256; d += 4) {
        float4 ev = *(const float4*)&Ev[d];
        float4 wx = *(const float4*)&Wx[e * 256 + d];
        float4 wz = *(const float4*)&Wz[e * 256 + d];
        ax += ev.x * wx.x + ev.y * wx.y + ev.z * wx.z + ev.w * wx.w;
        az += ev.x * wz.x + ev.y * wz.y + ev.z * wz.z + ev.w * wz.w;
    }
    float2 o; o.x = ax; o.y = 1.f / (1.f + __expf(-az));
    wgt[v * 256 + e] = o;
    Whf[v * 256 + e] = (_Float16)Wh[v * 256 + e];
}

// ---------------- Kernel 2: the serial recurrence ----------------
// 4 WGs x 16 batches, 8 waves/WG; wave wv owns dims [wv*32, wv*32+32).
// Wh chunk in registers (B-frags). h double-buffered in LDS. Tokens in LDS (u8,
// transposed). Gathers for t+2 are issued AFTER the last use of the current
// set, loading DIRECTLY into the consumed registers -> first consumer is two
// barriers later, so L2 latency is fully covered (no same-step vmcnt wait).
__global__ __launch_bounds__(512, 2) void rnn_k(
    const int* __restrict__ tokens, const float2* __restrict__ wgt,
    const _Float16* __restrict__ Whf, float* __restrict__ y)
{
    const int tid = threadIdx.x;
    const int wv  = tid >> 6;        // 0..7
    const int l   = tid & 63;
    const int n   = l & 15;          // MFMA col within 16-tile
    const int q   = l >> 4;          // 0..3
    const int bbase = blockIdx.x << 4;
    const int r0  = q << 2;          // C-layout rows this lane owns
    const int e0  = (wv << 5) + n;   // tile0 dim; tile1 = e0 + 16

    // B fragments: Wh[e][d0..d0+7], d0 = q*8 + ks*32
    half8 bf[2][8];
    #pragma unroll
    for (int tn = 0; tn < 2; ++tn) {
        const int e = e0 + (tn << 4);
        #pragma unroll
        for (int ks = 0; ks < 8; ++ks)
            bf[tn][ks] = *(const half8*)(Whf + e * 256 + (q << 3) + (ks << 5));
    }

    __shared__ _Float16 hbuf[2][16 * HST];          // 16.9 KB
    __shared__ unsigned char tokT[T_LEN * 16];      // 32 KB, tokT[t*16+row]

    // stage this WG's tokens transposed (one-time; coalesced along t)
    for (int i = tid; i < 16 * T_LEN; i += 512) {
        const int row = i >> 11, t = i & (T_LEN - 1);
        tokT[t * 16 + row] = (unsigned char)tokens[(bbase + row) * T_LEN + t];
    }
    for (int i = tid; i < 16 * HST; i += 512) hbuf[0][i] = (_Float16)0.f;
    LDS_BARRIER();

    // y byte-offset bases (32-bit voffsets against SGPR base)
    unsigned int yidx[4];
    #pragma unroll
    for (int i = 0; i < 4; ++i)
        yidx[i] = (unsigned)((bbase + r0 + i) * (T_LEN * 256) + e0) * 4u;

    const _Float16* hrd0 = &hbuf[0][n * HST + (q << 3)];
    const _Float16* hrd1 = &hbuf[1][n * HST + (q << 3)];
    _Float16* hw0 = &hbuf[0][r0 * HST + e0];
    _Float16* hw1 = &hbuf[1][r0 * HST + e0];

    // prologue: fill wx/gate for t=0 (even set) and t=1 (odd set)
    float wxe[4][2], ge[4][2], wxo[4][2], go[4][2];
    {
        const unsigned int t0 = *(const unsigned int*)&tokT[0 * 16 + r0];
        const unsigned int t1 = *(const unsigned int*)&tokT[1 * 16 + r0];
        #pragma unroll
        for (int i = 0; i < 4; ++i) {
            const int ta = (t0 >> (8 * i)) & 255;
            const int tb = (t1 >> (8 * i)) & 255;
            const float2* gp = wgt + ta * 256 + e0;
            float2 a = gp[0], b = gp[16];
            wxe[i][0] = a.x; ge[i][0] = a.y; wxe[i][1] = b.x; ge[i][1] = b.y;
            const float2* hp = wgt + tb * 256 + e0;
            float2 c = hp[0], d = hp[16];
            wxo[i][0] = c.x; go[i][0] = c.y; wxo[i][1] = d.x; go[i][1] = d.y;
        }
    }

// One timestep. Reads HRD (h_{t-1}), writes HW (h_t). Consumes WX/G, then
// refills them IN PLACE for tcur+2 (first consumer two barriers later).
#define STEP(tcur, HRD, HW, WX, G)                                             \
    {                                                                          \
        int tf = (tcur) + 2; if (tf > T_LEN - 1) tf = T_LEN - 1;               \
        const unsigned int tok4 = *(const unsigned int*)&tokT[tf * 16 + r0];   \
        floatx4 acc0a = 0.f, acc0b = 0.f, acc1a = 0.f, acc1b = 0.f;            \
        _Pragma("unroll")                                                      \
        for (int ks = 0; ks < 8; ks += 2) {                                    \
            half8 a0 = *(const half8*)(HRD + (ks << 5));                       \
            half8 a1 = *(const half8*)(HRD + ((ks + 1) << 5));                 \
            acc0a = __builtin_amdgcn_mfma_f32_16x16x32_f16(a0, bf[0][ks],     acc0a, 0, 0, 0); \
            acc1a = __builtin_amdgcn_mfma_f32_16x16x32_f16(a0, bf[1][ks],     acc1a, 0, 0, 0); \
            acc0b = __builtin_amdgcn_mfma_f32_16x16x32_f16(a1, bf[0][ks + 1], acc0b, 0, 0, 0); \
            acc1b = __builtin_amdgcn_mfma_f32_16x16x32_f16(a1, bf[1][ks + 1], acc1b, 0, 0, 0); \
        }                                                                      \
        /* consume WX/G: preact -> tanh -> y store + h to LDS */               \
        _Pragma("unroll")                                                      \
        for (int r = 0; r < 4; ++r) {                                          \
            float p0 = (acc0a[r] + acc0b[r]) + WX[r][0];                       \
            float p1 = (acc1a[r] + acc1b[r]) + WX[r][1];                       \
            float ex0 = __builtin_amdgcn_exp2f(p0 * 2.885390082f);             \
            float ex1 = __builtin_amdgcn_exp2f(p1 * 2.885390082f);             \
            float h0 = fmaf(__builtin_amdgcn_rcpf(ex0 + 1.f), -2.f, 1.f);      \
            float h1 = fmaf(__builtin_amdgcn_rcpf(ex1 + 1.f), -2.f, 1.f);      \
            __builtin_nontemporal_store(h0 * G[r][0], (float*)((char*)y + yidx[r]));        \
            __builtin_nontemporal_store(h1 * G[r][1], (float*)((char*)y + yidx[r]) + 16);   \
            HW[r * HST]      = (_Float16)h0;                                   \
            HW[r * HST + 16] = (_Float16)h1;                                   \
            yidx[r] += 1024;                                                   \
        }                                                                      \
        /* refill WX/G for tcur+2 AFTER last use: loads land in-place */       \
        _Pragma("unroll")                                                      \
        for (int i = 0; i < 4; ++i) {                                          \
            const int tk = (tok4 >> (8 * i)) & 255;                            \
            const float2* gp = wgt + tk * 256 + e0;                            \
            float2 a = gp[0], b = gp[16];                                      \
            WX[i][0] = a.x; G[i][0] = a.y;                                     \
            WX[i][1] = b.x; G[i][1] = b.y;                                     \
        }                                                                      \
        LDS_BARRIER();                                                         \
    }

    for (int t = 0; t < T_LEN; t += 2) {
        STEP(t,     hrd0, hw1, wxe, ge)   // even: h_{t-1} in buf0, h_t -> buf1
        STEP(t + 1, hrd1, hw0, wxo, go)   // odd:  h_t in buf1, h_{t+1} -> buf0
    }
#undef STEP
}

// ---------------- Kernel 3: tied head, in place ----------------
__device__ inline half8 cvt8(const float* p) {
    float4 u = *(const float4*)p;
    float4 w = *(const float4*)(p + 4);
    half8 r;
    r[0] = (_Float16)u.x; r[1] = (_Float16)u.y; r[2] = (_Float16)u.z; r[3] = (_Float16)u.w;
    r[4] = (_Float16)w.x; r[5] = (_Float16)w.y; r[6] = (_Float16)w.z; r[7] = (_Float16)w.w;
    return r;
}

__global__ __launch_bounds__(256) void logits_k(
    const float* __restrict__ E, float* __restrict__ io)
{
    const int tid = threadIdx.x;
    const int wv = tid >> 6;             // v-chunk base = wv*64
    const int l  = tid & 63;
    const int n  = l & 15, q = l >> 4;
    const int rowbase = blockIdx.x << 6; // 64 rows per WG
    const int k0base = q << 3;

    floatx4 acc[4][4];
    #pragma unroll
    for (int mt = 0; mt < 4; ++mt)
        #pragma unroll
        for (int tn = 0; tn < 4; ++tn) acc[mt][tn] = 0.f;

    #pragma unroll
    for (int ks = 0; ks < 8; ++ks) {
        const int k0 = (ks << 5) + k0base;
        half8 a[4], b[4];
        #pragma unroll
        for (int mt = 0; mt < 4; ++mt)
            a[mt] = cvt8(io + (rowbase + (mt << 4) + n) * 256 + k0);
        #pragma unroll
        for (int tn = 0; tn < 4; ++tn)
            b[tn] = cvt8(E + ((wv << 6) + (tn << 4) + n) * 256 + k0);
        #pragma unroll
        for (int mt = 0; mt < 4; ++mt)
            #pragma unroll
            for (int tn = 0; tn < 4; ++tn)
                acc[mt][tn] = __builtin_amdgcn_mfma_f32_16x16x32_f16(a[mt], b[tn], acc[mt][tn], 0, 0, 0);
    }
    __syncthreads();  // every wave's y reads complete before anyone overwrites
    #pragma unroll
    for (int mt = 0; mt < 4; ++mt)
        #pragma unroll
        for (int tn = 0; tn < 4; ++tn)
            #pragma unroll
            for (int r = 0; r < 4; ++r)
                io[(rowbase + (mt << 4) + (q << 2) + r) * 256 + (wv << 6) + (tn << 4) + n] = acc[mt][tn][r];
}

// ---------------- host ----------------
extern "C" void kernel_launch(void* const* d_in, const int* in_sizes, int n_in,
                              void* d_out, int out_size, void* d_ws, size_t ws_size,
                              hipStream_t stream) {
    const int*   tokens = (const int*)d_in[0];
    const float* E      = (const float*)d_in[1];
    const float* Wx     = (const float*)d_in[2];
    const float* Wh     = (const float*)d_in[3];
    const float* Wz     = (const float*)d_in[4];
    float* out = (float*)d_out;

    char* ws = (char*)d_ws;
    float2*   wgt = (float2*)ws;                      // 512 KiB
    _Float16* Whf = (_Float16*)(ws + (512 << 10));    // 128 KiB

    precompute_k<<<256, 256, 0, stream>>>(E, Wx, Wh, Wz, wgt, Whf);
    rnn_k<<<4, 512, 0, stream>>>(tokens, wgt, Whf, out);
    logits_k<<<2048, 256, 0, stream>>>(E, out);
}